// Round 1
// baseline (9926.484 us; speedup 1.0000x reference)
//
#include <hip/hip_runtime.h>

// Problem constants (from reference)
#define BB 2048   // batch
#define TT 128    // timesteps
#define VV 25     // input vocab/features
#define HH 512    // hidden
#define NC 100    // classes

__device__ __forceinline__ float fsigmoid(float x) {
    return 1.0f / (1.0f + __expf(-x));
}
// tanh(x) = 1 - 2/(exp(2x)+1); exp->inf => 1, exp->0 => -1 (no NaN)
__device__ __forceinline__ float ftanh(float x) {
    float e = __expf(2.0f * x);
    return 1.0f - 2.0f / (e + 1.0f);
}

// One LSTM timestep, fused: gates = h_in @ W_hh^T + msg[:,t,:] @ W_ih^T + (b_ih+b_hh)
// then cell update. Block tile: 64 batch rows x 32 j-cols (x 4 gates = 128 gate cols).
// Grid: (B/64, H/32) = (32, 16). 256 threads = 16x16 (ty, tx).
// Thread owns rows ty+16*ry (ry=0..3) and cols tx+16*m (m=0..7); gate = m>>1,
// jj = tx + 16*(m&1) -> each thread holds complete i,f,g,o quadruples in regs.
__global__ __launch_bounds__(256) void lstm_step(
    const float* __restrict__ msg, int t,
    const float* __restrict__ W_ih, const float* __restrict__ W_hh,
    const float* __restrict__ b_ih, const float* __restrict__ b_hh,
    const float* __restrict__ h_in, float* __restrict__ h_out,
    float* __restrict__ c)
{
    const int b0 = blockIdx.x * 64;
    const int j0 = blockIdx.y * 32;
    const int tid = threadIdx.x;
    const int tx = tid & 15;
    const int ty = tid >> 4;

    // +4 pad keeps float4 LDS ops 16B-aligned and breaks pow-2 bank strides
    __shared__ float At[64][36];    // A tile: [row][k]
    __shared__ float Wt[128][36];   // W tile: [gatecol][k], gatecol = gate*32+jj

    float acc[4][8];
    #pragma unroll
    for (int m = 0; m < 8; ++m) {
        int cc = tx + 16 * m;                       // 0..127
        int n = (cc >> 5) * HH + j0 + (cc & 31);    // row of W_* / bias index
        float bias = b_ih[n] + b_hh[n];
        #pragma unroll
        for (int ry = 0; ry < 4; ++ry) acc[ry][m] = bias;
    }

    // staging index precompute
    const int arow = tid >> 2;            // 0..63
    const int akc  = (tid & 3) << 3;      // 0,8,16,24  (8 floats each)
    const int wrow = tid >> 1;            // 0..127
    const int wkc  = (tid & 1) << 4;      // 0,16       (16 floats each)
    const int wn   = (wrow >> 5) * HH + j0 + (wrow & 31);

    // ---- K loop over hidden (h_in @ W_hh^T) ----
    for (int kt = 0; kt < HH; kt += 32) {
        const float* asrc = h_in + (size_t)(b0 + arow) * HH + kt + akc;
        float4 a0 = *(const float4*)asrc;
        float4 a1 = *(const float4*)(asrc + 4);
        const float* wsrc = W_hh + (size_t)wn * HH + kt + wkc;
        float4 w0 = *(const float4*)wsrc;
        float4 w1 = *(const float4*)(wsrc + 4);
        float4 w2 = *(const float4*)(wsrc + 8);
        float4 w3 = *(const float4*)(wsrc + 12);

        __syncthreads();   // previous tile's LDS reads done
        *(float4*)&At[arow][akc]     = a0;
        *(float4*)&At[arow][akc + 4] = a1;
        *(float4*)&Wt[wrow][wkc]      = w0;
        *(float4*)&Wt[wrow][wkc + 4]  = w1;
        *(float4*)&Wt[wrow][wkc + 8]  = w2;
        *(float4*)&Wt[wrow][wkc + 12] = w3;
        __syncthreads();

        #pragma unroll
        for (int k4 = 0; k4 < 32; k4 += 4) {
            float4 a[4];
            #pragma unroll
            for (int ry = 0; ry < 4; ++ry)
                a[ry] = *(const float4*)&At[ty + 16 * ry][k4];
            #pragma unroll
            for (int m = 0; m < 8; ++m) {
                float4 w = *(const float4*)&Wt[tx + 16 * m][k4];
                #pragma unroll
                for (int ry = 0; ry < 4; ++ry) {
                    acc[ry][m] = fmaf(a[ry].x, w.x, acc[ry][m]);
                    acc[ry][m] = fmaf(a[ry].y, w.y, acc[ry][m]);
                    acc[ry][m] = fmaf(a[ry].z, w.z, acc[ry][m]);
                    acc[ry][m] = fmaf(a[ry].w, w.w, acc[ry][m]);
                }
            }
        }
    }

    // ---- K=25 tail: msg[:,t,:] @ W_ih^T (zero-padded to 32) ----
    {
        float av[8];
        #pragma unroll
        for (int i = 0; i < 8; ++i) {
            int v = akc + i;
            av[i] = (v < VV) ? msg[((size_t)(b0 + arow) * TT + t) * VV + v] : 0.0f;
        }
        float wv[16];
        #pragma unroll
        for (int i = 0; i < 16; ++i) {
            int v = wkc + i;
            wv[i] = (v < VV) ? W_ih[(size_t)wn * VV + v] : 0.0f;
        }
        __syncthreads();
        #pragma unroll
        for (int i = 0; i < 8; ++i)  At[arow][akc + i] = av[i];
        #pragma unroll
        for (int i = 0; i < 16; ++i) Wt[wrow][wkc + i] = wv[i];
        __syncthreads();

        #pragma unroll
        for (int k4 = 0; k4 < 32; k4 += 4) {
            float4 a[4];
            #pragma unroll
            for (int ry = 0; ry < 4; ++ry)
                a[ry] = *(const float4*)&At[ty + 16 * ry][k4];
            #pragma unroll
            for (int m = 0; m < 8; ++m) {
                float4 w = *(const float4*)&Wt[tx + 16 * m][k4];
                #pragma unroll
                for (int ry = 0; ry < 4; ++ry) {
                    acc[ry][m] = fmaf(a[ry].x, w.x, acc[ry][m]);
                    acc[ry][m] = fmaf(a[ry].y, w.y, acc[ry][m]);
                    acc[ry][m] = fmaf(a[ry].z, w.z, acc[ry][m]);
                    acc[ry][m] = fmaf(a[ry].w, w.w, acc[ry][m]);
                }
            }
        }
    }

    // ---- cell update (all gates in registers) ----
    #pragma unroll
    for (int ry = 0; ry < 4; ++ry) {
        int b = b0 + ty + 16 * ry;
        #pragma unroll
        for (int half = 0; half < 2; ++half) {
            int jj = tx + 16 * half;
            size_t idx = (size_t)b * HH + j0 + jj;
            float i_ = fsigmoid(acc[ry][0 + half]);
            float f_ = fsigmoid(acc[ry][2 + half]);
            float g_ = ftanh(acc[ry][4 + half]);
            float o_ = fsigmoid(acc[ry][6 + half]);
            float cn = f_ * c[idx] + i_ * g_;
            c[idx] = cn;
            h_out[idx] = o_ * ftanh(cn);
        }
    }
}

// out[b, cls] = dot(h[b,:], W_fc[cls,:]) + b_fc[cls]
__global__ __launch_bounds__(128) void fc_kernel(
    const float* __restrict__ h, const float* __restrict__ W_fc,
    const float* __restrict__ b_fc, float* __restrict__ out)
{
    __shared__ float hs[HH];
    const int b = blockIdx.x;
    for (int i = threadIdx.x; i < HH; i += 128)
        hs[i] = h[(size_t)b * HH + i];
    __syncthreads();
    const int cls = threadIdx.x;
    if (cls < NC) {
        const float4* w = (const float4*)(W_fc + (size_t)cls * HH);
        const float4* hv = (const float4*)hs;
        float s = 0.0f;
        #pragma unroll 4
        for (int k = 0; k < HH / 4; ++k) {
            float4 a = hv[k], ww = w[k];
            s += a.x * ww.x + a.y * ww.y + a.z * ww.z + a.w * ww.w;
        }
        out[(size_t)b * NC + cls] = s + b_fc[cls];
    }
}

extern "C" void kernel_launch(void* const* d_in, const int* in_sizes, int n_in,
                              void* d_out, int out_size, void* d_ws, size_t ws_size,
                              hipStream_t stream) {
    const float* msg  = (const float*)d_in[0];
    const float* W_ih = (const float*)d_in[1];
    const float* W_hh = (const float*)d_in[2];
    const float* b_ih = (const float*)d_in[3];
    const float* b_hh = (const float*)d_in[4];
    const float* W_fc = (const float*)d_in[5];
    const float* b_fc = (const float*)d_in[6];
    float* out = (float*)d_out;

    // workspace: h0 | c | h1   (3 * B*H floats = 12 MB)
    float* h0 = (float*)d_ws;
    float* c  = h0 + (size_t)BB * HH;
    float* h1 = c  + (size_t)BB * HH;

    // h0 and c must start at zero (ws is poisoned each call); h1 fully
    // written at t=0 before any read.
    hipMemsetAsync(h0, 0, 2 * (size_t)BB * HH * sizeof(float), stream);

    float* hin = h0;
    float* hout = h1;
    for (int t = 0; t < TT; ++t) {
        lstm_step<<<dim3(BB / 64, HH / 32), 256, 0, stream>>>(
            msg, t, W_ih, W_hh, b_ih, b_hh, hin, hout, c);
        float* tmp = hin; hin = hout; hout = tmp;
    }
    fc_kernel<<<BB, 128, 0, stream>>>(hin, W_fc, b_fc, out);
}

// Round 2
// 4017.842 us; speedup vs baseline: 2.4706x; 2.4706x over previous
//
#include <hip/hip_runtime.h>

// Problem constants (from reference)
#define BB 2048   // batch
#define TT 128    // timesteps
#define VV 25     // input features
#define HH 512    // hidden
#define NC 100    // classes

typedef __attribute__((ext_vector_type(8))) short short8;
typedef __attribute__((ext_vector_type(4))) float f32x4;

__device__ __forceinline__ float fsigmoid(float x) {
    return 1.0f / (1.0f + __expf(-x));
}
// tanh(x) = 1 - 2/(exp(2x)+1); saturates cleanly, no NaN
__device__ __forceinline__ float ftanh(float x) {
    float e = __expf(2.0f * x);
    return 1.0f - 2.0f / (e + 1.0f);
}

// Split fp32 into bf16 hi + bf16 lo (RNE both). hi+lo carries ~16 mantissa
// bits; dropping lo*lo in the product leaves ~2^-16 relative error.
__device__ __forceinline__ void split2(float f, short& hi, short& lo) {
    unsigned u = __float_as_uint(f);
    unsigned hb = (u + 0x7FFFu + ((u >> 16) & 1u)) >> 16;
    float hf = __uint_as_float(hb << 16);
    float r = f - hf;                      // exact (Sterbenz)
    unsigned v = __float_as_uint(r);
    unsigned lb = (v + 0x7FFFu + ((v >> 16) & 1u)) >> 16;
    hi = (short)hb;
    lo = (short)lb;
}

// One LSTM timestep on matrix cores.
// gates[b, g*512+j] = h_in[b,:] @ W_hh[g*512+j,:] + msg[b,t,:] @ W_ih[...] + bias
// Block: 64 batch rows x (4 gates x 32 j-cols). Grid (2048/64, 512/32) = (32,16).
// 256 threads = 4 waves, wave w: wm=w&1 (32-row half), wn=w>>1 (16-col half).
// Wave tile: 2 m-tiles x 4 n-tiles of 16x16x32 bf16 MFMA; n-tile index == gate,
// so each thread's acc[tm][0..3][reg] is a complete (i,f,g,o) quadruple at one
// (b, j) -> fused cell update entirely in registers.
// fp32 accuracy via hi/lo split: acc += Ah*Bh + Ah*Bl + Al*Bh.
__global__ __launch_bounds__(256, 2) void lstm_step(
    const float* __restrict__ msg, int t,
    const float* __restrict__ W_ih, const float* __restrict__ W_hh,
    const float* __restrict__ b_ih, const float* __restrict__ b_hh,
    const float* __restrict__ h_in, float* __restrict__ h_out,
    float* __restrict__ c)
{
    const int b0 = blockIdx.x * 64;
    const int j0 = blockIdx.y * 32;
    const int tid = threadIdx.x;
    const int lane = tid & 63;
    const int w = tid >> 6;
    const int wm = w & 1, wn = w >> 1;
    const int col = lane & 15, quad = lane >> 4;

    // [row][k] bf16 tiles, k-contiguous; row stride 40 (pad 8) keeps 16B
    // alignment for b128 ops and makes frag reads 2-way-bank (free).
    __shared__ short Ah[64][40], Al[64][40];    // h tile hi/lo
    __shared__ short Bh[128][40], Bl[128][40];  // W tile hi/lo, row = gate*32+jj

    const int jj = j0 + wn * 16 + col;          // this thread's j column

    f32x4 acc[2][4];
    #pragma unroll
    for (int tn = 0; tn < 4; ++tn) {
        int n = tn * 512 + jj;
        float bias = b_ih[n] + b_hh[n];
        f32x4 bv = {bias, bias, bias, bias};
        acc[0][tn] = bv;
        acc[1][tn] = bv;
    }

    // staging assignment
    const int ar = tid >> 2, akc = (tid & 3) * 8;    // A: 64 rows x 32 k, 8/thread
    const int br = tid >> 1, bkc = (tid & 1) * 16;   // B: 128 rows x 32 k, 16/thread
    const int nb = (br >> 5) * 512 + j0 + (br & 31); // W row for B-tile row br
    const float* aptr = h_in + (size_t)(b0 + ar) * HH;
    const float* bptr = W_hh + (size_t)nb * HH;

    float ra[8], rb[16];
    // prefetch kt=0
    *(float4*)&ra[0] = *(const float4*)(aptr + akc);
    *(float4*)&ra[4] = *(const float4*)(aptr + akc + 4);
    #pragma unroll
    for (int i = 0; i < 4; ++i)
        *(float4*)&rb[4 * i] = *(const float4*)(bptr + bkc + 4 * i);

    float xa[8], xb[16];   // x-projection tail regs

    for (int kt = 0; kt < HH; kt += 32) {
        __syncthreads();   // previous iter's LDS reads done
        {   // convert + write staged tile
            short8 h8, l8;
            #pragma unroll
            for (int i = 0; i < 8; ++i) { short h_, l_; split2(ra[i], h_, l_); h8[i] = h_; l8[i] = l_; }
            *(short8*)&Ah[ar][akc] = h8;
            *(short8*)&Al[ar][akc] = l8;
            #pragma unroll
            for (int half = 0; half < 2; ++half) {
                short8 bh8, bl8;
                #pragma unroll
                for (int i = 0; i < 8; ++i) { short h_, l_; split2(rb[half * 8 + i], h_, l_); bh8[i] = h_; bl8[i] = l_; }
                *(short8*)&Bh[br][bkc + half * 8] = bh8;
                *(short8*)&Bl[br][bkc + half * 8] = bl8;
            }
        }
        __syncthreads();

        // prefetch next tile (overlaps with MFMA phase below)
        if (kt < HH - 32) {
            *(float4*)&ra[0] = *(const float4*)(aptr + kt + 32 + akc);
            *(float4*)&ra[4] = *(const float4*)(aptr + kt + 32 + akc + 4);
            #pragma unroll
            for (int i = 0; i < 4; ++i)
                *(float4*)&rb[4 * i] = *(const float4*)(bptr + kt + 32 + bkc + 4 * i);
        } else {
            // x-tail: msg[:,t,:] (K=25, zero-pad to 32) and W_ih
            #pragma unroll
            for (int i = 0; i < 8; ++i) {
                int v = akc + i;
                xa[i] = (v < VV) ? msg[((size_t)(b0 + ar) * TT + t) * VV + v] : 0.0f;
            }
            #pragma unroll
            for (int i = 0; i < 16; ++i) {
                int v = bkc + i;
                xb[i] = (v < VV) ? W_ih[(size_t)nb * VV + v] : 0.0f;
            }
        }

        // fragment loads + 24 MFMA
        short8 ahf[2], alf[2], bhf[4], blf[4];
        #pragma unroll
        for (int tm = 0; tm < 2; ++tm) {
            int row = wm * 32 + tm * 16 + col;
            ahf[tm] = *(const short8*)&Ah[row][quad * 8];
            alf[tm] = *(const short8*)&Al[row][quad * 8];
        }
        #pragma unroll
        for (int tn = 0; tn < 4; ++tn) {
            int row = tn * 32 + wn * 16 + col;
            bhf[tn] = *(const short8*)&Bh[row][quad * 8];
            blf[tn] = *(const short8*)&Bl[row][quad * 8];
        }
        #pragma unroll
        for (int tm = 0; tm < 2; ++tm)
            #pragma unroll
            for (int tn = 0; tn < 4; ++tn) {
                acc[tm][tn] = __builtin_amdgcn_mfma_f32_16x16x32_bf16(ahf[tm], bhf[tn], acc[tm][tn], 0, 0, 0);
                acc[tm][tn] = __builtin_amdgcn_mfma_f32_16x16x32_bf16(ahf[tm], blf[tn], acc[tm][tn], 0, 0, 0);
                acc[tm][tn] = __builtin_amdgcn_mfma_f32_16x16x32_bf16(alf[tm], bhf[tn], acc[tm][tn], 0, 0, 0);
            }
    }

    // ---- x-projection tail (K=32 padded) ----
    __syncthreads();
    {
        short8 h8, l8;
        #pragma unroll
        for (int i = 0; i < 8; ++i) { short h_, l_; split2(xa[i], h_, l_); h8[i] = h_; l8[i] = l_; }
        *(short8*)&Ah[ar][akc] = h8;
        *(short8*)&Al[ar][akc] = l8;
        #pragma unroll
        for (int half = 0; half < 2; ++half) {
            short8 bh8, bl8;
            #pragma unroll
            for (int i = 0; i < 8; ++i) { short h_, l_; split2(xb[half * 8 + i], h_, l_); bh8[i] = h_; bl8[i] = l_; }
            *(short8*)&Bh[br][bkc + half * 8] = bh8;
            *(short8*)&Bl[br][bkc + half * 8] = bl8;
        }
    }
    __syncthreads();
    {
        short8 ahf[2], alf[2], bhf[4], blf[4];
        #pragma unroll
        for (int tm = 0; tm < 2; ++tm) {
            int row = wm * 32 + tm * 16 + col;
            ahf[tm] = *(const short8*)&Ah[row][quad * 8];
            alf[tm] = *(const short8*)&Al[row][quad * 8];
        }
        #pragma unroll
        for (int tn = 0; tn < 4; ++tn) {
            int row = tn * 32 + wn * 16 + col;
            bhf[tn] = *(const short8*)&Bh[row][quad * 8];
            blf[tn] = *(const short8*)&Bl[row][quad * 8];
        }
        #pragma unroll
        for (int tm = 0; tm < 2; ++tm)
            #pragma unroll
            for (int tn = 0; tn < 4; ++tn) {
                acc[tm][tn] = __builtin_amdgcn_mfma_f32_16x16x32_bf16(ahf[tm], bhf[tn], acc[tm][tn], 0, 0, 0);
                acc[tm][tn] = __builtin_amdgcn_mfma_f32_16x16x32_bf16(ahf[tm], blf[tn], acc[tm][tn], 0, 0, 0);
                acc[tm][tn] = __builtin_amdgcn_mfma_f32_16x16x32_bf16(alf[tm], bhf[tn], acc[tm][tn], 0, 0, 0);
            }
    }

    // ---- cell update: acc[tm][0..3][reg] = (i,f,g,o) at one (b, jj) ----
    // C/D layout: col=lane&15 (=n), row=quad*4+reg (=m within tile)  [m89]
    #pragma unroll
    for (int tm = 0; tm < 2; ++tm) {
        #pragma unroll
        for (int reg = 0; reg < 4; ++reg) {
            int b = b0 + wm * 32 + tm * 16 + quad * 4 + reg;
            size_t idx = (size_t)b * HH + jj;
            float i_ = fsigmoid(acc[tm][0][reg]);
            float f_ = fsigmoid(acc[tm][1][reg]);
            float g_ = ftanh(acc[tm][2][reg]);
            float o_ = fsigmoid(acc[tm][3][reg]);
            float cn = f_ * c[idx] + i_ * g_;
            c[idx] = cn;
            h_out[idx] = o_ * ftanh(cn);
        }
    }
}

// out[b, cls] = dot(h[b,:], W_fc[cls,:]) + b_fc[cls]
__global__ __launch_bounds__(128) void fc_kernel(
    const float* __restrict__ h, const float* __restrict__ W_fc,
    const float* __restrict__ b_fc, float* __restrict__ out)
{
    __shared__ float hs[HH];
    const int b = blockIdx.x;
    for (int i = threadIdx.x; i < HH; i += 128)
        hs[i] = h[(size_t)b * HH + i];
    __syncthreads();
    const int cls = threadIdx.x;
    if (cls < NC) {
        const float4* w = (const float4*)(W_fc + (size_t)cls * HH);
        const float4* hv = (const float4*)hs;
        float s = 0.0f;
        #pragma unroll 4
        for (int k = 0; k < HH / 4; ++k) {
            float4 a = hv[k], ww = w[k];
            s += a.x * ww.x + a.y * ww.y + a.z * ww.z + a.w * ww.w;
        }
        out[(size_t)b * NC + cls] = s + b_fc[cls];
    }
}

extern "C" void kernel_launch(void* const* d_in, const int* in_sizes, int n_in,
                              void* d_out, int out_size, void* d_ws, size_t ws_size,
                              hipStream_t stream) {
    const float* msg  = (const float*)d_in[0];
    const float* W_ih = (const float*)d_in[1];
    const float* W_hh = (const float*)d_in[2];
    const float* b_ih = (const float*)d_in[3];
    const float* b_hh = (const float*)d_in[4];
    const float* W_fc = (const float*)d_in[5];
    const float* b_fc = (const float*)d_in[6];
    float* out = (float*)d_out;

    // workspace: h0 | c | h1   (3 * B*H floats = 12 MB)
    float* h0 = (float*)d_ws;
    float* c  = h0 + (size_t)BB * HH;
    float* h1 = c  + (size_t)BB * HH;

    // h0 and c must start at zero (ws is re-poisoned before every call)
    hipMemsetAsync(h0, 0, 2 * (size_t)BB * HH * sizeof(float), stream);

    float* hin = h0;
    float* hout = h1;
    for (int t = 0; t < TT; ++t) {
        lstm_step<<<dim3(BB / 64, HH / 32), 256, 0, stream>>>(
            msg, t, W_ih, W_hh, b_ih, b_hh, hin, hout, c);
        float* tmp = hin; hin = hout; hout = tmp;
    }
    fc_kernel<<<BB, 128, 0, stream>>>(hin, W_fc, b_fc, out);
}

// Round 3
// 2936.510 us; speedup vs baseline: 3.3804x; 1.3682x over previous
//
#include <hip/hip_runtime.h>

// Problem constants
#define BB 2048   // batch
#define TT 128    // timesteps
#define VV 25     // input features
#define HH 512    // hidden
#define NC 100    // classes

typedef __attribute__((ext_vector_type(8))) short short8;
typedef __attribute__((ext_vector_type(4))) float f32x4;

__device__ __forceinline__ float fsigmoid(float x) { return 1.0f / (1.0f + __expf(-x)); }
__device__ __forceinline__ float ftanh(float x) {
    float e = __expf(2.0f * x);
    return 1.0f - 2.0f / (e + 1.0f);
}

// fp32 -> bf16 hi + bf16 lo (RNE both); hi+lo carries ~16 mantissa bits.
__device__ __forceinline__ void split2(float f, short& hi, short& lo) {
    unsigned u = __float_as_uint(f);
    unsigned hb = (u + 0x7FFFu + ((u >> 16) & 1u)) >> 16;
    float hf = __uint_as_float(hb << 16);
    float r = f - hf;                      // exact
    unsigned v = __float_as_uint(r);
    unsigned lb = (v + 0x7FFFu + ((v >> 16) & 1u)) >> 16;
    hi = (short)hb;
    lo = (short)lb;
}

// ---- prep: one-time weight conversion (per launch) ----
__global__ __launch_bounds__(256) void prep_whh(const float* __restrict__ W,
                                                short* __restrict__ Wh, short* __restrict__ Wl) {
    int i = (blockIdx.x * 256 + threadIdx.x) * 4;       // 4*HH*HH elems, grid 1024
    float4 v = *(const float4*)(W + i);
    short h0,l0,h1,l1,h2,l2,h3,l3;
    split2(v.x,h0,l0); split2(v.y,h1,l1); split2(v.z,h2,l2); split2(v.w,h3,l3);
    short4 hv; hv.x=h0; hv.y=h1; hv.z=h2; hv.w=h3;
    short4 lv; lv.x=l0; lv.y=l1; lv.z=l2; lv.w=l3;
    *(short4*)(Wh + i) = hv;
    *(short4*)(Wl + i) = lv;
}

__global__ __launch_bounds__(256) void prep_wih(const float* __restrict__ W,
                                                short* __restrict__ Wh, short* __restrict__ Wl) {
    int i = blockIdx.x * 256 + threadIdx.x;             // 4H*32 = 65536, grid 256
    int row = i >> 5, k = i & 31;
    float v = (k < VV) ? W[row * VV + k] : 0.0f;
    short h, l; split2(v, h, l);
    Wh[i] = h; Wl[i] = l;
}

// One LSTM timestep on matrix cores, all operands pre-split into bf16 hi/lo.
// Block 64 batch x (4 gates x 32 j). Grid (32,16). 4 waves: wm=w&1 row-half,
// wn=w>>1 j-half. Wave: 2 m-tiles x 4 n-tiles (n-tile == gate) of 16x16x32.
// acc += Ah*Bh + Ah*Bl + Al*Bh (lo*lo dropped). K staged in 64-chunks.
__global__ __launch_bounds__(256, 2) void lstm_step(
    const float* __restrict__ msg, int t,
    const short* __restrict__ Wih_h, const short* __restrict__ Wih_l,
    const short* __restrict__ Whh_h, const short* __restrict__ Whh_l,
    const float* __restrict__ b_ih, const float* __restrict__ b_hh,
    const short* __restrict__ hin_h, const short* __restrict__ hin_l,
    short* __restrict__ hout_h, short* __restrict__ hout_l,
    float* __restrict__ c)
{
    const int b0 = blockIdx.x * 64;
    const int j0 = blockIdx.y * 32;
    const int tid = threadIdx.x;
    const int lane = tid & 63;
    const int w = tid >> 6;
    const int wm = w & 1, wn = w >> 1;
    const int col = lane & 15, quad = lane >> 4;

    // row stride 72 shorts = 144 B = 36 banks -> frag-read banks 4*(r%8): 2-way, free
    __shared__ short Ah[64][72], Al[64][72];     // h tile hi/lo, [row][k]
    __shared__ short Bh[128][72], Bl[128][72];   // W tile hi/lo, row = gate*32+jj

    const int jj = j0 + wn * 16 + col;

    f32x4 acc[2][4];
    #pragma unroll
    for (int tn = 0; tn < 4; ++tn) {
        int n = tn * HH + jj;
        float bias = b_ih[n] + b_hh[n];
        f32x4 bv = {bias, bias, bias, bias};
        acc[0][tn] = bv;
        acc[1][tn] = bv;
    }

    // staging: A 64 rows x 64 k, thread: row=tid>>2, chunks (tid&3)*8 and +32
    //          B 128 rows x 64 k, thread: row=tid>>1, 32 elems at (tid&1)*32
    const int ar = tid >> 2, ac8 = (tid & 3) * 8;
    const int br = tid >> 1, bc = (tid & 1) * 32;
    const int nb = (br >> 5) * HH + j0 + (br & 31);

    const short* aph = hin_h + (size_t)(b0 + ar) * HH;
    const short* apl = hin_l + (size_t)(b0 + ar) * HH;
    const short* bph = Whh_h + (size_t)nb * HH;
    const short* bpl = Whh_l + (size_t)nb * HH;

    short8 ra_h[2], ra_l[2], rb_h[4], rb_l[4];
    // prefetch kt=0
    ra_h[0] = *(const short8*)(aph + ac8);
    ra_h[1] = *(const short8*)(aph + ac8 + 32);
    ra_l[0] = *(const short8*)(apl + ac8);
    ra_l[1] = *(const short8*)(apl + ac8 + 32);
    #pragma unroll
    for (int j = 0; j < 4; ++j) {
        rb_h[j] = *(const short8*)(bph + bc + j * 8);
        rb_l[j] = *(const short8*)(bpl + bc + j * 8);
    }

    for (int kt = 0; kt < HH; kt += 64) {
        __syncthreads();   // prev iter's frag reads done
        *(short8*)&Ah[ar][ac8]      = ra_h[0];
        *(short8*)&Ah[ar][ac8 + 32] = ra_h[1];
        *(short8*)&Al[ar][ac8]      = ra_l[0];
        *(short8*)&Al[ar][ac8 + 32] = ra_l[1];
        #pragma unroll
        for (int j = 0; j < 4; ++j) {
            *(short8*)&Bh[br][bc + j * 8] = rb_h[j];
            *(short8*)&Bl[br][bc + j * 8] = rb_l[j];
        }
        __syncthreads();

        if (kt < HH - 64) {
            const int k2 = kt + 64;
            ra_h[0] = *(const short8*)(aph + k2 + ac8);
            ra_h[1] = *(const short8*)(aph + k2 + ac8 + 32);
            ra_l[0] = *(const short8*)(apl + k2 + ac8);
            ra_l[1] = *(const short8*)(apl + k2 + ac8 + 32);
            #pragma unroll
            for (int j = 0; j < 4; ++j) {
                rb_h[j] = *(const short8*)(bph + k2 + bc + j * 8);
                rb_l[j] = *(const short8*)(bpl + k2 + bc + j * 8);
            }
        } else {
            // tail prefetch: msg (K=25 padded to 32, split here) + pre-split W_ih
            float xv[8];
            const size_t mbase = ((size_t)(b0 + ar) * TT + t) * VV;
            #pragma unroll
            for (int i = 0; i < 8; ++i) {
                int v = ac8 + i;
                xv[i] = (v < VV) ? msg[mbase + v] : 0.0f;
            }
            short8 xh, xl;
            #pragma unroll
            for (int i = 0; i < 8; ++i) { short h_, l_; split2(xv[i], h_, l_); xh[i] = h_; xl[i] = l_; }
            ra_h[0] = xh; ra_l[0] = xl;
            const short* wih = Wih_h + (size_t)nb * 32 + (tid & 1) * 16;
            const short* wil = Wih_l + (size_t)nb * 32 + (tid & 1) * 16;
            rb_h[0] = *(const short8*)(wih);
            rb_h[1] = *(const short8*)(wih + 8);
            rb_l[0] = *(const short8*)(wil);
            rb_l[1] = *(const short8*)(wil + 8);
        }

        #pragma unroll
        for (int kk = 0; kk < 2; ++kk) {
            const int ka = kk * 32 + quad * 8;
            short8 ahf[2], alf[2], bhf[4], blf[4];
            #pragma unroll
            for (int tm = 0; tm < 2; ++tm) {
                int row = wm * 32 + tm * 16 + col;
                ahf[tm] = *(const short8*)&Ah[row][ka];
                alf[tm] = *(const short8*)&Al[row][ka];
            }
            #pragma unroll
            for (int tn = 0; tn < 4; ++tn) {
                int row = tn * 32 + wn * 16 + col;
                bhf[tn] = *(const short8*)&Bh[row][ka];
                blf[tn] = *(const short8*)&Bl[row][ka];
            }
            #pragma unroll
            for (int tm = 0; tm < 2; ++tm)
                #pragma unroll
                for (int tn = 0; tn < 4; ++tn) {
                    acc[tm][tn] = __builtin_amdgcn_mfma_f32_16x16x32_bf16(ahf[tm], bhf[tn], acc[tm][tn], 0, 0, 0);
                    acc[tm][tn] = __builtin_amdgcn_mfma_f32_16x16x32_bf16(ahf[tm], blf[tn], acc[tm][tn], 0, 0, 0);
                    acc[tm][tn] = __builtin_amdgcn_mfma_f32_16x16x32_bf16(alf[tm], bhf[tn], acc[tm][tn], 0, 0, 0);
                }
        }
    }

    // ---- x-projection tail (K=32) ----
    __syncthreads();
    *(short8*)&Ah[ar][ac8] = ra_h[0];
    *(short8*)&Al[ar][ac8] = ra_l[0];
    {
        const int tb = (tid & 1) * 16;
        *(short8*)&Bh[br][tb]     = rb_h[0];
        *(short8*)&Bh[br][tb + 8] = rb_h[1];
        *(short8*)&Bl[br][tb]     = rb_l[0];
        *(short8*)&Bl[br][tb + 8] = rb_l[1];
    }
    __syncthreads();
    {
        const int ka = quad * 8;
        short8 ahf[2], alf[2], bhf[4], blf[4];
        #pragma unroll
        for (int tm = 0; tm < 2; ++tm) {
            int row = wm * 32 + tm * 16 + col;
            ahf[tm] = *(const short8*)&Ah[row][ka];
            alf[tm] = *(const short8*)&Al[row][ka];
        }
        #pragma unroll
        for (int tn = 0; tn < 4; ++tn) {
            int row = tn * 32 + wn * 16 + col;
            bhf[tn] = *(const short8*)&Bh[row][ka];
            blf[tn] = *(const short8*)&Bl[row][ka];
        }
        #pragma unroll
        for (int tm = 0; tm < 2; ++tm)
            #pragma unroll
            for (int tn = 0; tn < 4; ++tn) {
                acc[tm][tn] = __builtin_amdgcn_mfma_f32_16x16x32_bf16(ahf[tm], bhf[tn], acc[tm][tn], 0, 0, 0);
                acc[tm][tn] = __builtin_amdgcn_mfma_f32_16x16x32_bf16(ahf[tm], blf[tn], acc[tm][tn], 0, 0, 0);
                acc[tm][tn] = __builtin_amdgcn_mfma_f32_16x16x32_bf16(alf[tm], bhf[tn], acc[tm][tn], 0, 0, 0);
            }
    }

    // ---- cell update; h written as bf16 hi/lo planes ----
    // C/D layout: col=lane&15 (=n), row=quad*4+reg [m89]
    #pragma unroll
    for (int tm = 0; tm < 2; ++tm) {
        #pragma unroll
        for (int reg = 0; reg < 4; ++reg) {
            int b = b0 + wm * 32 + tm * 16 + quad * 4 + reg;
            size_t idx = (size_t)b * HH + jj;
            float i_ = fsigmoid(acc[tm][0][reg]);
            float f_ = fsigmoid(acc[tm][1][reg]);
            float g_ = ftanh(acc[tm][2][reg]);
            float o_ = fsigmoid(acc[tm][3][reg]);
            float cn = f_ * c[idx] + i_ * g_;
            c[idx] = cn;
            float h = o_ * ftanh(cn);
            short hh_, hl_; split2(h, hh_, hl_);
            hout_h[idx] = hh_;
            hout_l[idx] = hl_;
        }
    }
}

// out[b, cls] = dot(h, W_fc[cls]) + b_fc[cls]; h reconstructed = hi + lo
__global__ __launch_bounds__(256) void fc_kernel(
    const short* __restrict__ h_hi, const short* __restrict__ h_lo,
    const float* __restrict__ W_fc, const float* __restrict__ b_fc,
    float* __restrict__ out)
{
    __shared__ float hs[2][HH];
    const int b0 = blockIdx.x * 2;
    for (int i = threadIdx.x; i < 2 * HH; i += 256) {
        int r = i >> 9, k = i & 511;
        size_t idx = (size_t)(b0 + r) * HH + k;
        unsigned uh = (unsigned)(unsigned short)h_hi[idx];
        unsigned ul = (unsigned)(unsigned short)h_lo[idx];
        hs[r][k] = __uint_as_float(uh << 16) + __uint_as_float(ul << 16);
    }
    __syncthreads();
    const int tid = threadIdx.x;
    if (tid < 2 * NC) {
        int r = tid / NC, cls = tid % NC;
        const float4* wv = (const float4*)(W_fc + (size_t)cls * HH);
        const float4* hv = (const float4*)hs[r];
        float s = 0.0f;
        #pragma unroll 4
        for (int k = 0; k < HH / 4; ++k) {
            float4 a = hv[k], ww = wv[k];
            s += a.x * ww.x + a.y * ww.y + a.z * ww.z + a.w * ww.w;
        }
        out[(size_t)(b0 + r) * NC + cls] = s + b_fc[cls];
    }
}

extern "C" void kernel_launch(void* const* d_in, const int* in_sizes, int n_in,
                              void* d_out, int out_size, void* d_ws, size_t ws_size,
                              hipStream_t stream) {
    const float* msg  = (const float*)d_in[0];
    const float* W_ih = (const float*)d_in[1];
    const float* W_hh = (const float*)d_in[2];
    const float* b_ih = (const float*)d_in[3];
    const float* b_hh = (const float*)d_in[4];
    const float* W_fc = (const float*)d_in[5];
    const float* b_fc = (const float*)d_in[6];
    float* out = (float*)d_out;

    // ws layout: c(f32 4MB) | h0h h0l h1h h1l (bf16 2MB each) |
    //            WhhH WhhL (2MB each) | WihH WihL (128KB each)  = 16.25 MB
    float* c   = (float*)d_ws;
    short* h0h = (short*)(c + (size_t)BB * HH);
    short* h0l = h0h + (size_t)BB * HH;
    short* h1h = h0l + (size_t)BB * HH;
    short* h1l = h1h + (size_t)BB * HH;
    short* WhhH = h1l + (size_t)BB * HH;
    short* WhhL = WhhH + (size_t)4 * HH * HH;
    short* WihH = WhhL + (size_t)4 * HH * HH;
    short* WihL = WihH + (size_t)4 * HH * 32;

    // zero c + h0 planes (contiguous): 4MB + 2MB + 2MB
    hipMemsetAsync(d_ws, 0, (size_t)BB * HH * 4 + (size_t)BB * HH * 2 * 2, stream);

    prep_whh<<<1024, 256, 0, stream>>>(W_hh, WhhH, WhhL);
    prep_wih<<<256, 256, 0, stream>>>(W_ih, WihH, WihL);

    short *hinh = h0h, *hinl = h0l, *houth = h1h, *houtl = h1l;
    for (int t = 0; t < TT; ++t) {
        lstm_step<<<dim3(BB / 64, HH / 32), 256, 0, stream>>>(
            msg, t, WihH, WihL, WhhH, WhhL, b_ih, b_hh,
            hinh, hinl, houth, houtl, c);
        short* tm1 = hinh; hinh = houth; houth = tm1;
        short* tm2 = hinl; hinl = houtl; houtl = tm2;
    }
    fc_kernel<<<BB / 2, 256, 0, stream>>>(hinh, hinl, W_fc, b_fc, out);
}

// Round 4
// 2467.330 us; speedup vs baseline: 4.0232x; 1.1902x over previous
//
#include <hip/hip_runtime.h>

// Problem constants
#define BB 2048   // batch
#define TT 128    // timesteps
#define VV 25     // input features
#define HH 512    // hidden
#define NC 100    // classes

typedef __attribute__((ext_vector_type(8))) short short8;
typedef __attribute__((ext_vector_type(4))) float f32x4;

__device__ __forceinline__ float fsigmoid(float x) { return 1.0f / (1.0f + __expf(-x)); }
__device__ __forceinline__ float ftanh(float x) {
    float e = __expf(2.0f * x);
    return 1.0f - 2.0f / (e + 1.0f);
}

// fp32 -> bf16 hi + bf16 lo (RNE both); hi+lo carries ~16 mantissa bits.
__device__ __forceinline__ void split2(float f, short& hi, short& lo) {
    unsigned u = __float_as_uint(f);
    unsigned hb = (u + 0x7FFFu + ((u >> 16) & 1u)) >> 16;
    float hf = __uint_as_float(hb << 16);
    float r = f - hf;                      // exact
    unsigned v = __float_as_uint(r);
    unsigned lb = (v + 0x7FFFu + ((v >> 16) & 1u)) >> 16;
    hi = (short)hb;
    lo = (short)lb;
}

// ---- prep: weights -> MFMA-fragment-native layout ----
// WT[kq][n] : 16B group = W[n][kq*8 .. kq*8+7]  (kq 0..63 = W_hh, 64..67 = W_ih pad32)
// B-frag load for chunk c: lane(col,quad) reads WT[(c*4+quad)][n0+col] -> 4x256B segments.
__global__ __launch_bounds__(256) void prep_whh_t(const float* __restrict__ W,
                                                  short* __restrict__ WTh, short* __restrict__ WTl) {
    int i = blockIdx.x * 256 + threadIdx.x;   // 2048 n x 64 kq = 131072, grid 512
    int n = i & 2047, kq = i >> 11;
    float v[8];
    #pragma unroll
    for (int j = 0; j < 8; ++j) v[j] = W[(size_t)n * HH + kq * 8 + j];
    short8 h8, l8;
    #pragma unroll
    for (int j = 0; j < 8; ++j) { short h_, l_; split2(v[j], h_, l_); h8[j] = h_; l8[j] = l_; }
    ((short8*)WTh)[(size_t)kq * 2048 + n] = h8;   // consecutive tid -> consecutive n: coalesced
    ((short8*)WTl)[(size_t)kq * 2048 + n] = l8;
}

__global__ __launch_bounds__(256) void prep_wih_t(const float* __restrict__ W,
                                                  short* __restrict__ WTh, short* __restrict__ WTl) {
    int i = blockIdx.x * 256 + threadIdx.x;   // 2048 n x 4 kq = 8192, grid 32
    int n = i & 2047, kq4 = i >> 11;
    float v[8];
    #pragma unroll
    for (int j = 0; j < 8; ++j) {
        int k = kq4 * 8 + j;
        v[j] = (k < VV) ? W[(size_t)n * VV + k] : 0.0f;
    }
    short8 h8, l8;
    #pragma unroll
    for (int j = 0; j < 8; ++j) { short h_, l_; split2(v[j], h_, l_); h8[j] = h_; l8[j] = l_; }
    ((short8*)WTh)[(size_t)(64 + kq4) * 2048 + n] = h8;
    ((short8*)WTl)[(size_t)(64 + kq4) * 2048 + n] = l8;
}

// One LSTM timestep. Block = 128 thr (2 waves) = 64 batch x 32 j (x4 gates).
// Grid (32, 16) = 512 blocks = 2 blocks/CU, 4 waves/CU.
// Wave tile: 4 m-tiles x 4 gates of 16x16x32 bf16; B-frags stream straight
// from L2 (WT frag layout, no LDS); A (h) stages via double-buffered LDS:
// ONE barrier per K64. 3-product hi/lo split: acc += Ah*Bh + Ah*Bl + Al*Bh.
__global__ __launch_bounds__(128, 1) void lstm_step(
    const float* __restrict__ msg, int t,
    const short* __restrict__ WTh, const short* __restrict__ WTl,
    const float* __restrict__ b_ih, const float* __restrict__ b_hh,
    const short* __restrict__ hin_h, const short* __restrict__ hin_l,
    short* __restrict__ hout_h, short* __restrict__ hout_l,
    float* __restrict__ c)
{
    const int b0 = blockIdx.x * 64;
    const int j0 = blockIdx.y * 32;
    const int tid = threadIdx.x;
    const int lane = tid & 63;
    const int w = tid >> 6;
    const int col = lane & 15, quad = lane >> 4;
    const int j0w = j0 + w * 16;
    const int jj = j0w + col;

    // [buf][plane][row][k]; row stride 72 (pad 8): frag reads 2-way bank = free
    __shared__ short Abuf[2][2][64][72];   // 36 KB

    f32x4 acc[4][4];   // [tm][gate]
    #pragma unroll
    for (int g = 0; g < 4; ++g) {
        float bias = b_ih[g * HH + jj] + b_hh[g * HH + jj];
        f32x4 bv = {bias, bias, bias, bias};
        #pragma unroll
        for (int tm = 0; tm < 4; ++tm) acc[tm][g] = bv;
    }

    // A staging mapping: thread -> (row = tid>>1, k-half = (tid&1)*32)
    const int arow = tid >> 1, ahalf = (tid & 1) * 32;
    const short* aph = hin_h + (size_t)(b0 + arow) * HH + ahalf;
    const short* apl = hin_l + (size_t)(b0 + arow) * HH + ahalf;

    const short8* WTh8 = (const short8*)WTh;
    const short8* WTl8 = (const short8*)WTl;
    int bidx[4];
    #pragma unroll
    for (int g = 0; g < 4; ++g) bidx[g] = quad * 2048 + g * HH + j0w + col;

    short8 Bh[2][4], Bl[2][4];   // B double-buffer regs
    short8 ra[8];                // staged A regs: [0..3]=hi, [4..7]=lo

    // ---- prologue ----
    #pragma unroll
    for (int i = 0; i < 4; ++i) { ra[i] = *(const short8*)(aph + i * 8); ra[4 + i] = *(const short8*)(apl + i * 8); }
    #pragma unroll
    for (int g = 0; g < 4; ++g) { Bh[0][g] = WTh8[bidx[g]]; Bl[0][g] = WTl8[bidx[g]]; }
    #pragma unroll
    for (int i = 0; i < 4; ++i) {
        *(short8*)&Abuf[0][0][arow][ahalf + i * 8] = ra[i];
        *(short8*)&Abuf[0][1][arow][ahalf + i * 8] = ra[4 + i];
    }
    #pragma unroll
    for (int i = 0; i < 4; ++i) { ra[i] = *(const short8*)(aph + 64 + i * 8); ra[4 + i] = *(const short8*)(apl + 64 + i * 8); }
    #pragma unroll
    for (int g = 0; g < 4; ++g) { Bh[1][g] = WTh8[8192 + bidx[g]]; Bl[1][g] = WTl8[8192 + bidx[g]]; }
    __syncthreads();

    float xv[16];                          // msg tail values
    const int xrow = tid & 63, xseg = tid >> 6;

    for (int it = 0; it < 8; ++it) {
        const int buf = it & 1;
        #pragma unroll
        for (int kk = 0; kk < 2; ++kk) {
            const int cchunk = it * 2 + kk;
            const int p = cchunk & 1;
            short8 ahf[4], alf[4];
            #pragma unroll
            for (int tm = 0; tm < 4; ++tm) {
                ahf[tm] = *(const short8*)&Abuf[buf][0][tm * 16 + col][kk * 32 + quad * 8];
                alf[tm] = *(const short8*)&Abuf[buf][1][tm * 16 + col][kk * 32 + quad * 8];
            }
            #pragma unroll
            for (int tm = 0; tm < 4; ++tm)
                #pragma unroll
                for (int g = 0; g < 4; ++g) {
                    acc[tm][g] = __builtin_amdgcn_mfma_f32_16x16x32_bf16(ahf[tm], Bh[p][g], acc[tm][g], 0, 0, 0);
                    acc[tm][g] = __builtin_amdgcn_mfma_f32_16x16x32_bf16(ahf[tm], Bl[p][g], acc[tm][g], 0, 0, 0);
                    acc[tm][g] = __builtin_amdgcn_mfma_f32_16x16x32_bf16(alf[tm], Bh[p][g], acc[tm][g], 0, 0, 0);
                }
            // prefetch B for chunk+2 into the slot just consumed (16 = Wih tail)
            if (cchunk + 2 <= 16) {
                const int ix = (cchunk + 2) * 8192;
                #pragma unroll
                for (int g = 0; g < 4; ++g) { Bh[p][g] = WTh8[ix + bidx[g]]; Bl[p][g] = WTl8[ix + bidx[g]]; }
            }
        }
        if (it < 7) {
            #pragma unroll
            for (int i = 0; i < 4; ++i) {          // ra holds chunk it+1
                *(short8*)&Abuf[buf ^ 1][0][arow][ahalf + i * 8] = ra[i];
                *(short8*)&Abuf[buf ^ 1][1][arow][ahalf + i * 8] = ra[4 + i];
            }
            if (it < 6) {
                const int kt = (it + 2) * 64;
                #pragma unroll
                for (int i = 0; i < 4; ++i) { ra[i] = *(const short8*)(aph + kt + i * 8); ra[4 + i] = *(const short8*)(apl + kt + i * 8); }
            } else {
                // it==6: load msg tail (K=25, pad to 32); row=tid&63, seg 16 k's each
                const size_t mb = ((size_t)(b0 + xrow) * TT + t) * VV;
                #pragma unroll
                for (int i = 0; i < 16; ++i) {
                    int k = xseg * 16 + i;
                    xv[i] = (k < VV) ? msg[mb + k] : 0.0f;
                }
            }
        } else {
            // it==7: stage x-tail into buf0 (safe: buf0 last read at it==6)
            short8 xh[2], xl[2];
            #pragma unroll
            for (int hx = 0; hx < 2; ++hx)
                #pragma unroll
                for (int i = 0; i < 8; ++i) {
                    short h_, l_; split2(xv[hx * 8 + i], h_, l_);
                    xh[hx][i] = h_; xl[hx][i] = l_;
                }
            #pragma unroll
            for (int hx = 0; hx < 2; ++hx) {
                *(short8*)&Abuf[0][0][xrow][xseg * 16 + hx * 8] = xh[hx];
                *(short8*)&Abuf[0][1][xrow][xseg * 16 + hx * 8] = xl[hx];
            }
        }
        __syncthreads();
    }

    // ---- x-projection tail: chunk 16 (K=32), buf0, B slot 0 ----
    {
        short8 ahf[4], alf[4];
        #pragma unroll
        for (int tm = 0; tm < 4; ++tm) {
            ahf[tm] = *(const short8*)&Abuf[0][0][tm * 16 + col][quad * 8];
            alf[tm] = *(const short8*)&Abuf[0][1][tm * 16 + col][quad * 8];
        }
        #pragma unroll
        for (int tm = 0; tm < 4; ++tm)
            #pragma unroll
            for (int g = 0; g < 4; ++g) {
                acc[tm][g] = __builtin_amdgcn_mfma_f32_16x16x32_bf16(ahf[tm], Bh[0][g], acc[tm][g], 0, 0, 0);
                acc[tm][g] = __builtin_amdgcn_mfma_f32_16x16x32_bf16(ahf[tm], Bl[0][g], acc[tm][g], 0, 0, 0);
                acc[tm][g] = __builtin_amdgcn_mfma_f32_16x16x32_bf16(alf[tm], Bh[0][g], acc[tm][g], 0, 0, 0);
            }
    }

    // ---- cell update; h written as bf16 hi/lo planes (row-major) ----
    // C/D layout: col=lane&15 (=n), row=quad*4+reg  [m89]
    #pragma unroll
    for (int tm = 0; tm < 4; ++tm) {
        #pragma unroll
        for (int reg = 0; reg < 4; ++reg) {
            int b = b0 + tm * 16 + quad * 4 + reg;
            size_t idx = (size_t)b * HH + jj;
            float i_ = fsigmoid(acc[tm][0][reg]);
            float f_ = fsigmoid(acc[tm][1][reg]);
            float g_ = ftanh(acc[tm][2][reg]);
            float o_ = fsigmoid(acc[tm][3][reg]);
            float cn = f_ * c[idx] + i_ * g_;
            c[idx] = cn;
            float h = o_ * ftanh(cn);
            short hh_, hl_; split2(h, hh_, hl_);
            hout_h[idx] = hh_;
            hout_l[idx] = hl_;
        }
    }
}

// out[b, cls] = dot(h, W_fc[cls]) + b_fc[cls]; h = hi + lo. 4 rows/block.
__global__ __launch_bounds__(256) void fc_kernel(
    const short* __restrict__ h_hi, const short* __restrict__ h_lo,
    const float* __restrict__ W_fc, const float* __restrict__ b_fc,
    float* __restrict__ out)
{
    __shared__ float hs[4][HH];
    const int b0 = blockIdx.x * 4;
    for (int i = threadIdx.x; i < 4 * HH; i += 256) {
        int r = i >> 9, k = i & 511;
        size_t idx = (size_t)(b0 + r) * HH + k;
        unsigned uh = (unsigned)(unsigned short)h_hi[idx];
        unsigned ul = (unsigned)(unsigned short)h_lo[idx];
        hs[r][k] = __uint_as_float(uh << 16) + __uint_as_float(ul << 16);
    }
    __syncthreads();
    const int tid = threadIdx.x;
    if (tid < 2 * NC) {
        int r = tid / NC, cls = tid % NC;
        const float4* wv = (const float4*)(W_fc + (size_t)cls * HH);
        const float4* h0 = (const float4*)hs[r];
        const float4* h1 = (const float4*)hs[r + 2];
        float s0 = 0.0f, s1 = 0.0f;
        #pragma unroll 4
        for (int k = 0; k < HH / 4; ++k) {
            float4 ww = wv[k];
            float4 a0 = h0[k], a1 = h1[k];
            s0 += a0.x * ww.x + a0.y * ww.y + a0.z * ww.z + a0.w * ww.w;
            s1 += a1.x * ww.x + a1.y * ww.y + a1.z * ww.z + a1.w * ww.w;
        }
        out[(size_t)(b0 + r) * NC + cls] = s0 + b_fc[cls];
        out[(size_t)(b0 + r + 2) * NC + cls] = s1 + b_fc[cls];
    }
}

extern "C" void kernel_launch(void* const* d_in, const int* in_sizes, int n_in,
                              void* d_out, int out_size, void* d_ws, size_t ws_size,
                              hipStream_t stream) {
    const float* msg  = (const float*)d_in[0];
    const float* W_ih = (const float*)d_in[1];
    const float* W_hh = (const float*)d_in[2];
    const float* b_ih = (const float*)d_in[3];
    const float* b_hh = (const float*)d_in[4];
    const float* W_fc = (const float*)d_in[5];
    const float* b_fc = (const float*)d_in[6];
    float* out = (float*)d_out;

    // ws: c(4MB) | h0h h0l h1h h1l (2MB ea) | WTh WTl (2.125MB ea) = 16.25MB
    float* c   = (float*)d_ws;
    short* h0h = (short*)(c + (size_t)BB * HH);
    short* h0l = h0h + (size_t)BB * HH;
    short* h1h = h0l + (size_t)BB * HH;
    short* h1l = h1h + (size_t)BB * HH;
    short* WTh = h1l + (size_t)BB * HH;
    short* WTl = WTh + (size_t)68 * 2048 * 8;

    // zero c + h0 planes (contiguous 8 MB)
    hipMemsetAsync(d_ws, 0, (size_t)BB * HH * 4 + (size_t)BB * HH * 2 * 2, stream);

    prep_whh_t<<<512, 256, 0, stream>>>(W_hh, WTh, WTl);
    prep_wih_t<<<32, 256, 0, stream>>>(W_ih, WTh, WTl);

    short *hinh = h0h, *hinl = h0l, *houth = h1h, *houtl = h1l;
    for (int t = 0; t < TT; ++t) {
        lstm_step<<<dim3(BB / 64, HH / 32), 128, 0, stream>>>(
            msg, t, WTh, WTl, b_ih, b_hh, hinh, hinl, houth, houtl, c);
        short* tm1 = hinh; hinh = houth; houth = tm1;
        short* tm2 = hinl; hinl = houtl; houtl = tm2;
    }
    fc_kernel<<<BB / 4, 256, 0, stream>>>(hinh, hinl, W_fc, b_fc, out);
}